// Round 8
// baseline (418.052 us; speedup 1.0000x reference)
//
#include <hip/hip_runtime.h>
#include <stdint.h>

typedef _Float16 f16;
typedef __attribute__((ext_vector_type(8))) _Float16 f16x8;
typedef __attribute__((ext_vector_type(4))) float f32x4;

// (1/sqrt(512)) * log2(e) folded into Q at projection time
#define QSCALE 0.0637587159f

__device__ __forceinline__ void gload16(const void* g, void* l) {
  __builtin_amdgcn_global_load_lds(
      (const __attribute__((address_space(1))) unsigned int*)(uintptr_t)g,
      (__attribute__((address_space(3))) unsigned int*)(uintptr_t)l,
      16, 0, 0);
}

// ---------------- prepass ----------------
__global__ __launch_bounds__(256) void k_cvt_x(const float* __restrict__ x,
                                               f16* __restrict__ xb) {
  const int i = (blockIdx.x * 256 + threadIdx.x) * 8;
  const float4 a = *(const float4*)(x + i);
  const float4 b = *(const float4*)(x + i + 4);
  f16x8 o;
  o[0] = (f16)a.x; o[1] = (f16)a.y; o[2] = (f16)a.z; o[3] = (f16)a.w;
  o[4] = (f16)b.x; o[5] = (f16)b.y; o[6] = (f16)b.z; o[7] = (f16)b.w;
  *(f16x8*)(xb + i) = o;
}

// Wq,Wk -> Wqkt[e'][d] (e'<512: Wq col e', else Wk col e'-512); Wv -> Wvt[e][d]
__global__ __launch_bounds__(256) void k_tw(const float* __restrict__ Wq,
                                            const float* __restrict__ Wk,
                                            const float* __restrict__ Wv,
                                            f16* __restrict__ Wqkt,
                                            f16* __restrict__ Wvt) {
  const int t = blockIdx.x * 256 + threadIdx.x;   // 768*256 = 196608
  const int mat = t >> 16;
  const int rem = t & 65535;
  const int e = rem & 511;
  const int d4 = (rem >> 9) << 2;
  const float* W = (mat == 0) ? Wq : (mat == 1 ? Wk : Wv);
  f16* dst = (mat == 0) ? (Wqkt + e * 512)
           : (mat == 1 ? (Wqkt + (512 + e) * 512) : (Wvt + e * 512));
#pragma unroll
  for (int i = 0; i < 4; i++) dst[d4 + i] = (f16)W[(d4 + i) * 512 + e];
}

// ---------------- shared 128x128x512 GEMM core ----------------
__device__ __forceinline__ void gemm_tile(const f16* __restrict__ Ag,
                                          const f16* __restrict__ Btg,
                                          f32x4 acc[4][4]) {
  __shared__ __align__(16) f16 As[128 * 64];
  __shared__ __align__(16) f16 Bs[128 * 64];
  const int lane = threadIdx.x & 63;
  const int w = threadIdx.x >> 6;
  const int wr = (w >> 1) * 64;
  const int wc = (w & 1) * 64;
#pragma unroll
  for (int i = 0; i < 4; i++)
#pragma unroll
    for (int j = 0; j < 4; j++) acc[i][j] = (f32x4){0.f, 0.f, 0.f, 0.f};

  for (int kt = 0; kt < 8; ++kt) {
#pragma unroll
    for (int i = 0; i < 4; i++) {
      const int r = w * 32 + i * 8 + (lane >> 3);
      const int src = kt * 64 + (((lane & 7) * 8) ^ ((r & 7) << 3));
      gload16(Ag + r * 512 + src, &As[(w * 32 + i * 8) * 64]);
      gload16(Btg + r * 512 + src, &Bs[(w * 32 + i * 8) * 64]);
    }
    __syncthreads();
#pragma unroll
    for (int ks = 0; ks < 2; ++ks) {
      f16x8 a[4], bfr[4];
#pragma unroll
      for (int i = 0; i < 4; i++) {
        const int row = wr + i * 16 + (lane & 15);
        a[i] = *(const f16x8*)&As[row * 64 +
                 ((ks * 32 + 8 * (lane >> 4)) ^ ((row & 7) << 3))];
      }
#pragma unroll
      for (int j = 0; j < 4; j++) {
        const int row = wc + j * 16 + (lane & 15);
        bfr[j] = *(const f16x8*)&Bs[row * 64 +
                 ((ks * 32 + 8 * (lane >> 4)) ^ ((row & 7) << 3))];
      }
#pragma unroll
      for (int i = 0; i < 4; i++)
#pragma unroll
        for (int j = 0; j < 4; j++)
          acc[i][j] = __builtin_amdgcn_mfma_f32_16x16x32_f16(a[i], bfr[j],
                                                             acc[i][j], 0, 0, 0);
    }
    __syncthreads();
  }
}

// ---------------- Q|K projection ----------------
__global__ __launch_bounds__(256) void k_qk_proj(
    const f16* __restrict__ xb, const f16* __restrict__ Wqkt,
    const float* __restrict__ bq, const float* __restrict__ bk,
    f16* __restrict__ Q, f16* __restrict__ K) {
  const int rt = blockIdx.x, ct = blockIdx.y;
  f32x4 acc[4][4];
  gemm_tile(xb + rt * 128 * 512, Wqkt + ct * 128 * 512, acc);
  const int lane = threadIdx.x & 63;
  const int w = threadIdx.x >> 6;
  const int wr = (w >> 1) * 64, wc = (w & 1) * 64;
  const bool isQ = (ct < 4);
  const float* bias = isQ ? bq : bk;
  f16* dst = isQ ? Q : K;
  const int cb = (ct & 3) * 128;
  const float qs = isQ ? QSCALE : 1.0f;
#pragma unroll
  for (int j = 0; j < 4; j++) {
    const int col = cb + wc + j * 16 + (lane & 15);
    const float bb = bias[col];
#pragma unroll
    for (int i = 0; i < 4; i++) {
      const int nbase = rt * 128 + wr + i * 16 + 4 * (lane >> 4);
#pragma unroll
      for (int r = 0; r < 4; r++) {
        float v = fmaxf(acc[i][j][r] + bb, 0.f) * qs;
        dst[(nbase + r) * 512 + col] = (f16)v;
      }
    }
  }
}

// ---------------- V projection (stores V^T per batch) ----------------
__global__ __launch_bounds__(256) void k_v_proj(
    const f16* __restrict__ Wvt, const f16* __restrict__ xb,
    const float* __restrict__ bv, f16* __restrict__ Vt) {
  const int rt = blockIdx.x;  // e tile (0..3)
  const int ct = blockIdx.y;  // token tile (0..127)
  f32x4 acc[4][4];
  gemm_tile(Wvt + rt * 128 * 512, xb + ct * 128 * 512, acc);
  const int lane = threadIdx.x & 63;
  const int w = threadIdx.x >> 6;
  const int wr = (w >> 1) * 64, wc = (w & 1) * 64;
#pragma unroll
  for (int i = 0; i < 4; i++) {
    const int ebase = rt * 128 + wr + i * 16 + 4 * (lane >> 4);
#pragma unroll
    for (int j = 0; j < 4; j++) {
      const int n = ct * 128 + wc + j * 16 + (lane & 15);
      const int b = n >> 11, nb = n & 2047;
#pragma unroll
      for (int r = 0; r < 4; r++) {
        const int e = ebase + r;
        float v = fmaxf(acc[i][j][r] + bv[e], 0.f);
        Vt[(b * 512 + e) * 2048 + nb] = (f16)v;
      }
    }
  }
}

// ---------------- flash attention: split-K, 8 waves, 2 waves/SIMD ----------
// Waves 0-3 (grp A) process even KV tiles, waves 4-7 (grp B) odd tiles, for
// the same 64 q-rows; private (m,l,o) per group, merged in the epilogue.
// LDS: K0[32][512] | K1 | V0[512][32] | V1 | Ps[8][16*72]  = 149,504 B
__global__ __launch_bounds__(512, 2) void k_attn(
    const f16* __restrict__ Q, const f16* __restrict__ K,
    const f16* __restrict__ Vt, float* __restrict__ out) {
  __shared__ __align__(16) f16 smem[74752];
  const int b = blockIdx.x & 7;                     // batch -> XCD pin
  const int qb = blockIdx.x >> 3;
  const int lane = threadIdx.x & 63;
  const int w = threadIdx.x >> 6;                   // 0..7
  const int grp = w >> 2;                           // 0: even tiles, 1: odd
  const int wq = w & 3;                             // q sub-block (16 rows)
  const f16* Qg = Q + (b * 2048 + qb * 64) * 512;
  const f16* Kg = K + b * 2048 * 512;
  const f16* Vg = Vt + b * 512 * 2048;
  f16* const Ps = smem + 65536 + w * 1152;
  f16* const Ks = smem + grp * 16384;               // this group's K buffer
  f16* const Vs = smem + 32768 + grp * 16384;       // this group's V buffer

  // stage Q (64 rows x 1KB) into the K0|K1 region; pull fragments to regs
#pragma unroll
  for (int i = 0; i < 8; i++) {
    const int r = w * 8 + i;
    gload16(Qg + r * 512 + ((lane * 8) ^ ((r & 7) << 3)), &smem[r * 512]);
  }
  __syncthreads();
  f16x8 qf[16];
  {
    const int row = wq * 16 + (lane & 15);
#pragma unroll
    for (int ks = 0; ks < 16; ++ks)
      qf[ks] = *(const f16x8*)&smem[row * 512 +
               ((ks * 32 + 8 * (lane >> 4)) ^ ((row & 7) << 3))];
  }
  __syncthreads();

  // prologue: each group stages its tile (A: tile 0, B: tile 1)
  {
    const int t = grp;
#pragma unroll
    for (int i = 0; i < 8; i++) {
      const int r = wq * 8 + i;
      gload16(Kg + (t * 32 + r) * 512 + ((lane * 8) ^ ((r & 7) << 3)),
              Ks + r * 512);
    }
#pragma unroll
    for (int i = 0; i < 8; i++) {
      const int row = wq * 128 + i * 16 + (lane >> 2);
      const int col = (8 * (lane & 3)) ^ (8 * ((row >> 1) & 3));
      gload16(Vg + row * 2048 + t * 32 + col, Vs + (wq * 128 + i * 16) * 32);
    }
  }
  __syncthreads();

  f32x4 o[32];
#pragma unroll
  for (int i = 0; i < 32; i++) o[i] = (f32x4){0.f, 0.f, 0.f, 0.f};
  float m[4] = {-1e30f, -1e30f, -1e30f, -1e30f};
  float l[4] = {0.f, 0.f, 0.f, 0.f};

  for (int p = 0; p < 32; ++p) {
    // S = Q' K^T on this group's tile (16q x 32k per wave)
    f32x4 s[2];
#pragma unroll
    for (int c = 0; c < 2; c++) s[c] = (f32x4){0.f, 0.f, 0.f, 0.f};
#pragma unroll
    for (int ks = 0; ks < 16; ++ks) {
#pragma unroll
      for (int c = 0; c < 2; c++) {
        const int row = c * 16 + (lane & 15);
        const f16x8 kf = *(const f16x8*)&Ks[row * 512 +
                        ((ks * 32 + 8 * (lane >> 4)) ^ ((row & 7) << 3))];
        s[c] = __builtin_amdgcn_mfma_f32_16x16x32_f16(qf[ks], kf, s[c], 0, 0, 0);
      }
    }

    // online softmax; rows live across the 16-lane (lane&15) group
    float sc[4];
#pragma unroll
    for (int r = 0; r < 4; r++) {
      float v = fmaxf(s[0][r], s[1][r]);
      v = fmaxf(v, __shfl_xor(v, 1));
      v = fmaxf(v, __shfl_xor(v, 2));
      v = fmaxf(v, __shfl_xor(v, 4));
      v = fmaxf(v, __shfl_xor(v, 8));
      const float nm = fmaxf(m[r], v);
      sc[r] = exp2f(m[r] - nm);
      m[r] = nm;
      float rs = 0.f;
      const int prow = 4 * (lane >> 4) + r;
#pragma unroll
      for (int c = 0; c < 2; c++) {
        const float pv = exp2f(s[c][r] - nm);
        Ps[prow * 72 + c * 16 + (lane & 15)] = (f16)pv;
        rs += pv;
      }
      rs += __shfl_xor(rs, 1);
      rs += __shfl_xor(rs, 2);
      rs += __shfl_xor(rs, 4);
      rs += __shfl_xor(rs, 8);
      l[r] = l[r] * sc[r] + rs;
    }
    {
      const f32x4 scv = {sc[0], sc[1], sc[2], sc[3]};
#pragma unroll
      for (int i = 0; i < 32; i++) o[i] *= scv;
    }

    // O += P V
    const f16x8 pf = *(const f16x8*)&Ps[(lane & 15) * 72 + 8 * (lane >> 4)];
#pragma unroll
    for (int dt = 0; dt < 32; ++dt) {
      const int row = dt * 16 + (lane & 15);
      const f16x8 v0 = *(const f16x8*)&Vs[row * 32 +
                      ((8 * (lane >> 4)) ^ (8 * ((row >> 1) & 3)))];
      o[dt] = __builtin_amdgcn_mfma_f32_16x16x32_f16(pf, v0, o[dt], 0, 0, 0);
    }

    // stage this group's next tile (single-buffered per group)
    if (p < 31) {
      __syncthreads();   // all waves done reading before overwrite
      const int t = 2 * (p + 1) + grp;
#pragma unroll
      for (int i = 0; i < 8; i++) {
        const int r = wq * 8 + i;
        gload16(Kg + (t * 32 + r) * 512 + ((lane * 8) ^ ((r & 7) << 3)),
                Ks + r * 512);
      }
#pragma unroll
      for (int i = 0; i < 8; i++) {
        const int row = wq * 128 + i * 16 + (lane >> 2);
        const int col = (8 * (lane & 3)) ^ (8 * ((row >> 1) & 3));
        gload16(Vg + row * 2048 + t * 32 + col, Vs + (wq * 128 + i * 16) * 32);
      }
      __syncthreads(); // drains vmcnt: staged data visible
    }
  }

  // ---- merge epilogue: A publishes partials, B merges + stores ----
  __syncthreads();   // all compute done; K/V LDS now dead
  float* const obuf = (float*)smem;              // 32768 floats (K+V region)
  float* const mlbuf = (float*)(smem + 65536);   // 128 floats (in wave0 Ps)
  if (grp == 0) {
    if ((lane & 15) == 0) {
#pragma unroll
      for (int r = 0; r < 4; r++) {
        const int row = wq * 16 + 4 * (lane >> 4) + r;
        mlbuf[row] = m[r];
        mlbuf[64 + row] = l[r];
      }
    }
    // o1 transposed: [col][4-row group] so both sides use b128
#pragma unroll
    for (int dt = 0; dt < 32; ++dt) {
      const int idx = wq * 8192 + (dt * 16 + (lane & 15)) * 16 + 4 * (lane >> 4);
      *(f32x4*)&obuf[idx] = o[dt];
    }
  }
  __syncthreads();
  if (grp == 1) {
    f32x4 fAv, fBv;
#pragma unroll
    for (int r = 0; r < 4; r++) {
      const int row = wq * 16 + 4 * (lane >> 4) + r;
      const float m1 = mlbuf[row], l1 = mlbuf[64 + row];
      const float M = fmaxf(m1, m[r]);
      const float a = exp2f(m1 - M);
      const float bb = exp2f(m[r] - M);
      const float rv = 1.0f / (l1 * a + l[r] * bb);
      fAv[r] = a * rv;
      fBv[r] = bb * rv;
    }
    float* ob = out + ((b * 2048 + qb * 64 + wq * 16 + 4 * (lane >> 4)) * 512) +
                (lane & 15);
#pragma unroll
    for (int dt = 0; dt < 32; ++dt) {
      const int idx = wq * 8192 + (dt * 16 + (lane & 15)) * 16 + 4 * (lane >> 4);
      const f32x4 o1v = *(const f32x4*)&obuf[idx];
      const f32x4 res = o1v * fAv + o[dt] * fBv;
#pragma unroll
      for (int r = 0; r < 4; r++) ob[r * 512 + dt * 16] = res[r];
    }
  }
}

// ---------------- launch ----------------
extern "C" void kernel_launch(void* const* d_in, const int* in_sizes, int n_in,
                              void* d_out, int out_size, void* d_ws, size_t ws_size,
                              hipStream_t stream) {
  const float* x  = (const float*)d_in[0];
  const float* Wq = (const float*)d_in[1];
  const float* bq = (const float*)d_in[2];
  const float* Wk = (const float*)d_in[3];
  const float* bk = (const float*)d_in[4];
  const float* Wv = (const float*)d_in[5];
  const float* bv = (const float*)d_in[6];
  float* out = (float*)d_out;
  char* ws = (char*)d_ws;

  f16* xb   = (f16*)(ws);                                   // 16 MB
  f16* Wqkt = (f16*)(ws + 16777216);                        // 1 MB
  f16* Wvt  = (f16*)(ws + 16777216 + 1048576);              // 0.5 MB
  f16* Qb   = (f16*)(ws + 18350080);                        // 16 MB
  f16* Kb   = (f16*)(ws + 18350080 + 16777216);             // 16 MB
  f16* Vtb  = (f16*)(ws + 18350080 + 2 * 16777216);         // 16 MB  (total ~69 MB)

  // x: B*N*D = 8*2048*512 = 8,388,608 floats; 8 elts/thread -> 4096 blocks
  hipLaunchKernelGGL(k_cvt_x, dim3(4096), dim3(256), 0, stream, x, xb);
  hipLaunchKernelGGL(k_tw, dim3(768), dim3(256), 0, stream, Wq, Wk, Wv, Wqkt, Wvt);
  hipLaunchKernelGGL(k_qk_proj, dim3(128, 8), dim3(256), 0, stream, xb, Wqkt, bq, bk, Qb, Kb);
  hipLaunchKernelGGL(k_v_proj, dim3(4, 128), dim3(256), 0, stream, Wvt, xb, bv, Vtb);
  hipLaunchKernelGGL(k_attn, dim3(256), dim3(512), 0, stream, Qb, Kb, Vtb, out);
}

// Round 11
// 393.697 us; speedup vs baseline: 1.0619x; 1.0619x over previous
//
#include <hip/hip_runtime.h>
#include <stdint.h>

typedef _Float16 f16;
typedef __attribute__((ext_vector_type(8))) _Float16 f16x8;
typedef __attribute__((ext_vector_type(4))) float f32x4;

// (1/sqrt(512)) * log2(e) folded into Q at projection time
#define QSCALE 0.0637587159f

__device__ __forceinline__ void gload16(const void* g, void* l) {
  __builtin_amdgcn_global_load_lds(
      (const __attribute__((address_space(1))) unsigned int*)(uintptr_t)g,
      (__attribute__((address_space(3))) unsigned int*)(uintptr_t)l,
      16, 0, 0);
}

// ---------------- prepass ----------------
__global__ __launch_bounds__(256) void k_cvt_x(const float* __restrict__ x,
                                               f16* __restrict__ xb) {
  const int i = (blockIdx.x * 256 + threadIdx.x) * 8;
  const float4 a = *(const float4*)(x + i);
  const float4 b = *(const float4*)(x + i + 4);
  f16x8 o;
  o[0] = (f16)a.x; o[1] = (f16)a.y; o[2] = (f16)a.z; o[3] = (f16)a.w;
  o[4] = (f16)b.x; o[5] = (f16)b.y; o[6] = (f16)b.z; o[7] = (f16)b.w;
  *(f16x8*)(xb + i) = o;
}

// Wq,Wk -> Wqkt[e'][d] (e'<512: Wq col e', else Wk col e'-512); Wv -> Wvt[e][d]
__global__ __launch_bounds__(256) void k_tw(const float* __restrict__ Wq,
                                            const float* __restrict__ Wk,
                                            const float* __restrict__ Wv,
                                            f16* __restrict__ Wqkt,
                                            f16* __restrict__ Wvt) {
  const int t = blockIdx.x * 256 + threadIdx.x;   // 768*256 = 196608
  const int mat = t >> 16;
  const int rem = t & 65535;
  const int e = rem & 511;
  const int d4 = (rem >> 9) << 2;
  const float* W = (mat == 0) ? Wq : (mat == 1 ? Wk : Wv);
  f16* dst = (mat == 0) ? (Wqkt + e * 512)
           : (mat == 1 ? (Wqkt + (512 + e) * 512) : (Wvt + e * 512));
#pragma unroll
  for (int i = 0; i < 4; i++) dst[d4 + i] = (f16)W[(d4 + i) * 512 + e];
}

// ---------------- shared 128x128x512 GEMM core ----------------
__device__ __forceinline__ void gemm_tile(const f16* __restrict__ Ag,
                                          const f16* __restrict__ Btg,
                                          f32x4 acc[4][4]) {
  __shared__ __align__(16) f16 As[128 * 64];
  __shared__ __align__(16) f16 Bs[128 * 64];
  const int lane = threadIdx.x & 63;
  const int w = threadIdx.x >> 6;
  const int wr = (w >> 1) * 64;
  const int wc = (w & 1) * 64;
#pragma unroll
  for (int i = 0; i < 4; i++)
#pragma unroll
    for (int j = 0; j < 4; j++) acc[i][j] = (f32x4){0.f, 0.f, 0.f, 0.f};

  for (int kt = 0; kt < 8; ++kt) {
#pragma unroll
    for (int i = 0; i < 4; i++) {
      const int r = w * 32 + i * 8 + (lane >> 3);
      const int src = kt * 64 + (((lane & 7) * 8) ^ ((r & 7) << 3));
      gload16(Ag + r * 512 + src, &As[(w * 32 + i * 8) * 64]);
      gload16(Btg + r * 512 + src, &Bs[(w * 32 + i * 8) * 64]);
    }
    __syncthreads();
#pragma unroll
    for (int ks = 0; ks < 2; ++ks) {
      f16x8 a[4], bfr[4];
#pragma unroll
      for (int i = 0; i < 4; i++) {
        const int row = wr + i * 16 + (lane & 15);
        a[i] = *(const f16x8*)&As[row * 64 +
                 ((ks * 32 + 8 * (lane >> 4)) ^ ((row & 7) << 3))];
      }
#pragma unroll
      for (int j = 0; j < 4; j++) {
        const int row = wc + j * 16 + (lane & 15);
        bfr[j] = *(const f16x8*)&Bs[row * 64 +
                 ((ks * 32 + 8 * (lane >> 4)) ^ ((row & 7) << 3))];
      }
#pragma unroll
      for (int i = 0; i < 4; i++)
#pragma unroll
        for (int j = 0; j < 4; j++)
          acc[i][j] = __builtin_amdgcn_mfma_f32_16x16x32_f16(a[i], bfr[j],
                                                             acc[i][j], 0, 0, 0);
    }
    __syncthreads();
  }
}

// ---------------- Q|K projection ----------------
__global__ __launch_bounds__(256) void k_qk_proj(
    const f16* __restrict__ xb, const f16* __restrict__ Wqkt,
    const float* __restrict__ bq, const float* __restrict__ bk,
    f16* __restrict__ Q, f16* __restrict__ K) {
  const int rt = blockIdx.x, ct = blockIdx.y;
  f32x4 acc[4][4];
  gemm_tile(xb + rt * 128 * 512, Wqkt + ct * 128 * 512, acc);
  const int lane = threadIdx.x & 63;
  const int w = threadIdx.x >> 6;
  const int wr = (w >> 1) * 64, wc = (w & 1) * 64;
  const bool isQ = (ct < 4);
  const float* bias = isQ ? bq : bk;
  f16* dst = isQ ? Q : K;
  const int cb = (ct & 3) * 128;
  const float qs = isQ ? QSCALE : 1.0f;
#pragma unroll
  for (int j = 0; j < 4; j++) {
    const int col = cb + wc + j * 16 + (lane & 15);
    const float bb = bias[col];
#pragma unroll
    for (int i = 0; i < 4; i++) {
      const int nbase = rt * 128 + wr + i * 16 + 4 * (lane >> 4);
#pragma unroll
      for (int r = 0; r < 4; r++) {
        float v = fmaxf(acc[i][j][r] + bb, 0.f) * qs;
        dst[(nbase + r) * 512 + col] = (f16)v;
      }
    }
  }
}

// ---------------- V projection (stores V^T per batch) ----------------
__global__ __launch_bounds__(256) void k_v_proj(
    const f16* __restrict__ Wvt, const f16* __restrict__ xb,
    const float* __restrict__ bv, f16* __restrict__ Vt) {
  const int rt = blockIdx.x;  // e tile (0..3)
  const int ct = blockIdx.y;  // token tile (0..127)
  f32x4 acc[4][4];
  gemm_tile(Wvt + rt * 128 * 512, xb + ct * 128 * 512, acc);
  const int lane = threadIdx.x & 63;
  const int w = threadIdx.x >> 6;
  const int wr = (w >> 1) * 64, wc = (w & 1) * 64;
#pragma unroll
  for (int i = 0; i < 4; i++) {
    const int ebase = rt * 128 + wr + i * 16 + 4 * (lane >> 4);
#pragma unroll
    for (int j = 0; j < 4; j++) {
      const int n = ct * 128 + wc + j * 16 + (lane & 15);
      const int b = n >> 11, nb = n & 2047;
#pragma unroll
      for (int r = 0; r < 4; r++) {
        const int e = ebase + r;
        float v = fmaxf(acc[i][j][r] + bv[e], 0.f);
        Vt[(b * 512 + e) * 2048 + nb] = (f16)v;
      }
    }
  }
}

// ---------------- flash attention: 8 waves, k-split pairs, 2 waves/SIMD ----
// 256 blocks x 512 threads. Wave w: qsub = w&3 (16 q-rows), half = w>>2
// (k-cols 0-31 / 32-63 of each KVBLK=64 tile). Pairs (qsub, half=0/1) merge
// in-LDS at the end (round-8-proven epilogue). 1 block/CU, 8 waves = 2/SIMD.
// LDS (f16 units): K[64][512] @0 | V[512][64] @32768 | ml @65536 (512B) |
// Ps 8x1152 @65792  -> 75008 f16 = 150,016 B.
__global__ __launch_bounds__(512) void k_attn(
    const f16* __restrict__ Q, const f16* __restrict__ K,
    const f16* __restrict__ Vt, float* __restrict__ out) {
  __shared__ __align__(16) f16 smem[75008];
  const int b = blockIdx.x & 7;                     // batch -> XCD pin
  const int qb = blockIdx.x >> 3;                   // q-block (64 rows)
  const int lane = threadIdx.x & 63;
  const int w = threadIdx.x >> 6;                   // 0..7
  const int qsub = w & 3;
  const int half = w >> 2;
  const f16* Qg = Q + (b * 2048 + qb * 64) * 512;
  const f16* Kg = K + b * 2048 * 512;
  const f16* Vg = Vt + b * 512 * 2048;
  f16* const Ks = smem;                             // [64][512]
  f16* const Vs = smem + 32768;                     // [512][64]
  f16* const Ps = smem + 65792 + w * 1152;

  // stage Q (64 rows x 1KB) into the K region; pull fragments to registers
#pragma unroll
  for (int i = 0; i < 8; i++) {
    const int r = w * 8 + i;
    gload16(Qg + r * 512 + ((lane * 8) ^ ((r & 7) << 3)), &smem[r * 512]);
  }
  __syncthreads();
  f16x8 qf[16];
  {
    const int row = qsub * 16 + (lane & 15);
#pragma unroll
    for (int ks = 0; ks < 16; ++ks)
      qf[ks] = *(const f16x8*)&smem[row * 512 +
               ((ks * 32 + 8 * (lane >> 4)) ^ ((row & 7) << 3))];
  }
  __syncthreads();

  // prologue: stage tile 0 (K 64x1KB, V 512x128B; 8 waves cooperate)
#pragma unroll
  for (int i = 0; i < 8; i++) {
    const int r = w * 8 + i;
    gload16(Kg + r * 512 + ((lane * 8) ^ ((r & 7) << 3)), Ks + r * 512);
  }
#pragma unroll
  for (int i = 0; i < 8; i++) {
    const int row = w * 64 + i * 8 + (lane >> 3);
    const int col = (8 * (lane & 7)) ^ ((row & 7) << 3);
    gload16(Vg + row * 2048 + col, Vs + (w * 64 + i * 8) * 64);
  }
  __syncthreads();

  f32x4 o[32];
#pragma unroll
  for (int i = 0; i < 32; i++) o[i] = (f32x4){0.f, 0.f, 0.f, 0.f};
  float m[4] = {-1e30f, -1e30f, -1e30f, -1e30f};
  float l[4] = {0.f, 0.f, 0.f, 0.f};

  for (int kt = 0; kt < 32; ++kt) {
    // S = Q' K^T on this wave's 32 k-cols (16q x 32k)
    f32x4 s[2];
#pragma unroll
    for (int c = 0; c < 2; c++) s[c] = (f32x4){0.f, 0.f, 0.f, 0.f};
#pragma unroll
    for (int ks = 0; ks < 16; ++ks) {
#pragma unroll
      for (int c = 0; c < 2; c++) {
        const int row = half * 32 + c * 16 + (lane & 15);
        const f16x8 kf = *(const f16x8*)&Ks[row * 512 +
                        ((ks * 32 + 8 * (lane >> 4)) ^ ((row & 7) << 3))];
        s[c] = __builtin_amdgcn_mfma_f32_16x16x32_f16(qf[ks], kf, s[c], 0, 0, 0);
      }
    }

    // online softmax over this wave's 32 cols
    float sc[4];
#pragma unroll
    for (int r = 0; r < 4; r++) {
      float v = fmaxf(s[0][r], s[1][r]);
      v = fmaxf(v, __shfl_xor(v, 1));
      v = fmaxf(v, __shfl_xor(v, 2));
      v = fmaxf(v, __shfl_xor(v, 4));
      v = fmaxf(v, __shfl_xor(v, 8));
      const float nm = fmaxf(m[r], v);
      sc[r] = exp2f(m[r] - nm);
      m[r] = nm;
      float rs = 0.f;
      const int prow = 4 * (lane >> 4) + r;
#pragma unroll
      for (int c = 0; c < 2; c++) {
        const float pv = exp2f(s[c][r] - nm);
        Ps[prow * 72 + c * 16 + (lane & 15)] = (f16)pv;
        rs += pv;
      }
      rs += __shfl_xor(rs, 1);
      rs += __shfl_xor(rs, 2);
      rs += __shfl_xor(rs, 4);
      rs += __shfl_xor(rs, 8);
      l[r] = l[r] * sc[r] + rs;
    }
    {
      const f32x4 scv = {sc[0], sc[1], sc[2], sc[3]};
#pragma unroll
      for (int i = 0; i < 32; i++) o[i] *= scv;
    }

    // O += P V on this wave's 32 k-rows of V
    const f16x8 pf = *(const f16x8*)&Ps[(lane & 15) * 72 + 8 * (lane >> 4)];
#pragma unroll
    for (int dt = 0; dt < 32; ++dt) {
      const int row = dt * 16 + (lane & 15);
      const f16x8 v0 = *(const f16x8*)&Vs[row * 64 +
                      ((half * 32 + 8 * (lane >> 4)) ^ ((row & 7) << 3))];
      o[dt] = __builtin_amdgcn_mfma_f32_16x16x32_f16(pf, v0, o[dt], 0, 0, 0);
    }

    // stage next tile (single-buffered; all 8 waves cooperate)
    if (kt < 31) {
      __syncthreads();   // all waves done reading before overwrite
#pragma unroll
      for (int i = 0; i < 8; i++) {
        const int r = w * 8 + i;
        gload16(Kg + ((kt + 1) * 64 + r) * 512 + ((lane * 8) ^ ((r & 7) << 3)),
                Ks + r * 512);
      }
#pragma unroll
      for (int i = 0; i < 8; i++) {
        const int row = w * 64 + i * 8 + (lane >> 3);
        const int col = (8 * (lane & 7)) ^ ((row & 7) << 3);
        gload16(Vg + row * 2048 + (kt + 1) * 64 + col,
                Vs + (w * 64 + i * 8) * 64);
      }
      __syncthreads(); // drains vmcnt: staged data visible
    }
  }

  // ---- in-LDS pairwise merge (round-8 epilogue): half0 publishes, half1 merges
  __syncthreads();   // all compute done; K/V LDS now dead
  float* const obuf = (float*)smem;              // 32768 floats (K+V region)
  float* const mlb = (float*)(smem + 65536);     // 128 floats
  if (half == 0) {
    if ((lane & 15) == 0) {
#pragma unroll
      for (int r = 0; r < 4; r++) {
        const int row = qsub * 16 + 4 * (lane >> 4) + r;
        mlb[row] = m[r];
        mlb[64 + row] = l[r];
      }
    }
    // o(half0) transposed: [col][4-row group] so both sides use 16B vectors
#pragma unroll
    for (int dt = 0; dt < 32; ++dt) {
      const int idx = qsub * 8192 + (dt * 16 + (lane & 15)) * 16 + 4 * (lane >> 4);
      *(f32x4*)&obuf[idx] = o[dt];
    }
  }
  __syncthreads();
  if (half == 1) {
    f32x4 fAv, fBv;
#pragma unroll
    for (int r = 0; r < 4; r++) {
      const int row = qsub * 16 + 4 * (lane >> 4) + r;
      const float m1 = mlb[row], l1 = mlb[64 + row];
      const float M = fmaxf(m1, m[r]);
      const float a = exp2f(m1 - M);
      const float bb = exp2f(m[r] - M);
      const float rv = 1.0f / (l1 * a + l[r] * bb);
      fAv[r] = a * rv;
      fBv[r] = bb * rv;
    }
    float* ob = out + ((b * 2048 + qb * 64 + qsub * 16 + 4 * (lane >> 4)) * 512) +
                (lane & 15);
#pragma unroll
    for (int dt = 0; dt < 32; ++dt) {
      const int idx = qsub * 8192 + (dt * 16 + (lane & 15)) * 16 + 4 * (lane >> 4);
      const f32x4 o1v = *(const f32x4*)&obuf[idx];
      const f32x4 res = o1v * fAv + o[dt] * fBv;
#pragma unroll
      for (int r = 0; r < 4; r++) ob[r * 512 + dt * 16] = res[r];
    }
  }
}

// ---------------- launch ----------------
extern "C" void kernel_launch(void* const* d_in, const int* in_sizes, int n_in,
                              void* d_out, int out_size, void* d_ws, size_t ws_size,
                              hipStream_t stream) {
  const float* x  = (const float*)d_in[0];
  const float* Wq = (const float*)d_in[1];
  const float* bq = (const float*)d_in[2];
  const float* Wk = (const float*)d_in[3];
  const float* bk = (const float*)d_in[4];
  const float* Wv = (const float*)d_in[5];
  const float* bv = (const float*)d_in[6];
  float* out = (float*)d_out;
  char* ws = (char*)d_ws;

  f16* xb   = (f16*)(ws);                                   // 16 MB
  f16* Wqkt = (f16*)(ws + 16777216);                        // 1 MB
  f16* Wvt  = (f16*)(ws + 16777216 + 1048576);              // 0.5 MB
  f16* Qb   = (f16*)(ws + 18350080);                        // 16 MB
  f16* Kb   = (f16*)(ws + 18350080 + 16777216);             // 16 MB
  f16* Vtb  = (f16*)(ws + 18350080 + 2 * 16777216);         // 16 MB  (total ~69 MB)

  // x: B*N*D = 8*2048*512 = 8,388,608 floats; 8 elts/thread -> 4096 blocks
  hipLaunchKernelGGL(k_cvt_x, dim3(4096), dim3(256), 0, stream, x, xb);
  hipLaunchKernelGGL(k_tw, dim3(768), dim3(256), 0, stream, Wq, Wk, Wv, Wqkt, Wvt);
  hipLaunchKernelGGL(k_qk_proj, dim3(128, 8), dim3(256), 0, stream, xb, Wqkt, bq, bk, Qb, Kb);
  hipLaunchKernelGGL(k_v_proj, dim3(4, 128), dim3(256), 0, stream, Wvt, xb, bv, Vtb);
  hipLaunchKernelGGL(k_attn, dim3(256), dim3(512), 0, stream, Qb, Kb, Vtb, out);
}